// Round 17
// baseline (73.246 us; speedup 1.0000x reference)
//
#include <hip/hip_runtime.h>

#define NN 10000
#define NE 640000
#define DIM 128
#define HB 256                        // hist/scatter blocks
#define HEPB (NE / HB)                // 2500 edges per block
#define FCN 32                        // nodes per fc block
#define FCB ((NN + FCN - 1) / FCN)    // 313 fc blocks
#define PAD 128                       // compact CSR per-node slot bound

static __device__ __forceinline__ unsigned short f2bf(float f) {
    unsigned u = __float_as_uint(f);
    unsigned r = (u + 0x7FFFu + ((u >> 16) & 1u)) >> 16;   // RNE
    return (unsigned short)r;
}
static __device__ __forceinline__ float bfhi(unsigned u) { return __uint_as_float(u & 0xFFFF0000u); }
static __device__ __forceinline__ float bflo(unsigned u) { return __uint_as_float(u << 16); }

// ---------------------------------------------------------------------------
// K1: blocks 0..255 = LDS histogram of dst -> bhcnt8[v][b] (uchar);
//     blocks 256..568 = fc (LDS-transposed W, proven R13-R16).
// ---------------------------------------------------------------------------
__global__ __launch_bounds__(512, 2) void histfc_kernel(
    const int* __restrict__ dst, unsigned char* __restrict__ bhcnt8,
    const float* __restrict__ h, const float* __restrict__ W,
    const float* __restrict__ Wa, unsigned short* __restrict__ zb,
    float* __restrict__ e)
{
    __shared__ int smem[10240];                    // 40 KB, aliased per role
    const int bid = blockIdx.x, t = threadIdx.x;

    if (bid < HB) {
        // ---- histogram ----
        int* lh = smem;
        int4* l4 = (int4*)lh;
        for (int i = t; i < NN / 4; i += 512) l4[i] = make_int4(0, 0, 0, 0);
        __syncthreads();
        const int4* d4 = (const int4*)(dst + bid * HEPB);
        for (int i = t; i < HEPB / 4; i += 512) {
            int4 d = d4[i];
            atomicAdd(&lh[d.x], 1); atomicAdd(&lh[d.y], 1);
            atomicAdd(&lh[d.z], 1); atomicAdd(&lh[d.w], 1);
        }
        __syncthreads();
        for (int v = t; v < NN; v += 512) {
            int c = lh[v];
            bhcnt8[(size_t)v * HB + bid] = (unsigned char)(c < 255 ? c : 255);
        }
    } else {
        // ---- fc: z(bf16) = h @ W^T via LDS-transposed W tiles ----
        float* hs = (float*)smem;                  // [32][128] = 16 KB
        float* wt = hs + FCN * DIM;                // [32][132] = 16.5 KB
        const int jl = t & 31, jq = jl * 4;
        const int ng = t >> 5;                     // 0..15, 2 nodes each
        const int i0 = (bid - HB) * FCN;

        const float4* h4 = (const float4*)h;
        float4* hs4 = (float4*)hs;
        #pragma unroll
        for (int p = 0; p < 2; ++p) {              // 32 nodes x 32 float4
            int u = t + p * 512;
            int gi = i0 + (u >> 5);
            hs4[u] = (gi < NN) ? h4[(size_t)gi * 32 + (u & 31)]
                               : make_float4(0.f, 0.f, 0.f, 0.f);
        }

        const float4* W4 = (const float4*)W;
        float acc[2][4] = {};
        for (int kt = 0; kt < 4; ++kt) {           // 4 k-tiles of 32
            __syncthreads();                       // hs ready / wt reuse guard
            #pragma unroll
            for (int p = 0; p < 2; ++p) {          // 128 rows x 8 float4
                int idx = t + p * 512;
                int row = idx >> 3, q4 = idx & 7;
                float4 wv = W4[(size_t)row * 32 + kt * 8 + q4];   // coalesced
                wt[(q4 * 4 + 0) * 132 + row] = wv.x;
                wt[(q4 * 4 + 1) * 132 + row] = wv.y;
                wt[(q4 * 4 + 2) * 132 + row] = wv.z;
                wt[(q4 * 4 + 3) * 132 + row] = wv.w;
            }
            __syncthreads();
            #pragma unroll
            for (int kk4 = 0; kk4 < 8; ++kk4) {
                float4 wj0 = *(const float4*)&wt[(kk4 * 4 + 0) * 132 + jq];
                float4 wj1 = *(const float4*)&wt[(kk4 * 4 + 1) * 132 + jq];
                float4 wj2 = *(const float4*)&wt[(kk4 * 4 + 2) * 132 + jq];
                float4 wj3 = *(const float4*)&wt[(kk4 * 4 + 3) * 132 + jq];
                #pragma unroll
                for (int m = 0; m < 2; ++m) {
                    float4 hv = *(const float4*)&hs[(2 * ng + m) * DIM + kt * 32 + kk4 * 4];
                    acc[m][0] += hv.x * wj0.x + hv.y * wj1.x + hv.z * wj2.x + hv.w * wj3.x;
                    acc[m][1] += hv.x * wj0.y + hv.y * wj1.y + hv.z * wj2.y + hv.w * wj3.y;
                    acc[m][2] += hv.x * wj0.z + hv.y * wj1.z + hv.z * wj2.z + hv.w * wj3.z;
                    acc[m][3] += hv.x * wj0.w + hv.y * wj1.w + hv.z * wj2.w + hv.w * wj3.w;
                }
            }
        }

        const float a0 = Wa[jq], a1 = Wa[jq + 1], a2 = Wa[jq + 2], a3 = Wa[jq + 3];
        #pragma unroll
        for (int m = 0; m < 2; ++m) {
            int gi = i0 + 2 * ng + m;
            float ep = acc[m][0] * a0 + acc[m][1] * a1 + acc[m][2] * a2 + acc[m][3] * a3;
            #pragma unroll
            for (int o = 16; o > 0; o >>= 1) ep += __shfl_xor(ep, o, 64);
            if (gi < NN) {
                ushort4 zo;
                zo.x = f2bf(acc[m][0]); zo.y = f2bf(acc[m][1]);
                zo.z = f2bf(acc[m][2]); zo.w = f2bf(acc[m][3]);
                *(ushort4*)&zb[(size_t)gi * DIM + jq] = zo;
                if (jl == 0) e[gi] = ep;
            }
        }
    }
}

// ---------------------------------------------------------------------------
// K2: colscan. One wave per node v: lane l reads cells 4l..4l+3 (uchar4,
// coalesced 256B/wave), 6-shuffle scan -> exclusive prefix8[v][b] (uchar4
// write back, coalesced) + deg8[v].
// ---------------------------------------------------------------------------
__global__ __launch_bounds__(256) void colscan_kernel(
    const unsigned char* __restrict__ bhcnt8, unsigned char* __restrict__ prefix8,
    unsigned char* __restrict__ deg8)
{
    const int lane = threadIdx.x & 63, w = threadIdx.x >> 6;
    const int v = blockIdx.x * 4 + w;              // 2500 * 4 = 10000 exact
    uchar4 cc = *(const uchar4*)(bhcnt8 + (size_t)v * HB + 4 * lane);
    int c0 = cc.x, c1 = cc.y, c2 = cc.z, c3 = cc.w;
    int tl = c0 + c1 + c2 + c3;
    int x = tl;
    #pragma unroll
    for (int o = 1; o <= 32; o <<= 1) {
        int y = __shfl_up(x, o, 64);
        if (lane >= o) x += y;
    }
    int excl = x - tl;
    uchar4 pp;
    pp.x = (unsigned char)excl;
    pp.y = (unsigned char)(excl + c0);
    pp.z = (unsigned char)(excl + c0 + c1);
    pp.w = (unsigned char)(excl + c0 + c1 + c2);
    *(uchar4*)(prefix8 + (size_t)v * HB + 4 * lane) = pp;
    if (lane == 63) deg8[v] = (unsigned char)(x < 255 ? x : 255);
}

// ---------------------------------------------------------------------------
// K3: scatter. 256 blocks; lcur seeded from own prefix column; LDS rank ->
// compact write esrc16[d*128 + r] (2.56 MB region, L2-resident).
// ---------------------------------------------------------------------------
__global__ __launch_bounds__(512) void scatter_kernel(
    const int* __restrict__ src, const int* __restrict__ dst,
    const unsigned char* __restrict__ prefix8, unsigned short* __restrict__ esrc16)
{
    __shared__ int lcur[NN];
    const int b = blockIdx.x, t = threadIdx.x;
    for (int v = t; v < NN; v += 512) lcur[v] = prefix8[(size_t)v * HB + b];
    __syncthreads();
    const int4* d4 = (const int4*)(dst + b * HEPB);
    const int4* s4 = (const int4*)(src + b * HEPB);
    for (int i = t; i < HEPB / 4; i += 512) {
        int4 d = d4[i]; int4 s = s4[i];
        int r;
        r = atomicAdd(&lcur[d.x], 1); if (r < PAD) esrc16[(d.x << 7) + r] = (unsigned short)s.x;
        r = atomicAdd(&lcur[d.y], 1); if (r < PAD) esrc16[(d.y << 7) + r] = (unsigned short)s.y;
        r = atomicAdd(&lcur[d.z], 1); if (r < PAD) esrc16[(d.z << 7) + r] = (unsigned short)s.z;
        r = atomicAdd(&lcur[d.w], 1); if (r < PAD) esrc16[(d.w << 7) + r] = (unsigned short)s.w;
    }
}

// ---------------------------------------------------------------------------
// K4: agg. 4 waves/block, one node per wave, no barriers. Dense CSR: one
// coalesced uint/lane covers 128 slots; softmax + weighted bf16 gather.
// ---------------------------------------------------------------------------
__global__ __launch_bounds__(256) void agg_kernel(
    const unsigned char* __restrict__ deg8, const unsigned short* __restrict__ esrc16,
    const float* __restrict__ e, const unsigned* __restrict__ zb32,
    float* __restrict__ out)
{
    __shared__ int   es[4][PAD];
    __shared__ float ew[4][PAD];
    const int w = threadIdx.x >> 6, lane = threadIdx.x & 63;
    const int v = blockIdx.x * 4 + w;              // 2500*4 = 10000 exact
    int* esw = es[w];
    float* eww = ew[w];
    int deg = deg8[v];
    if (deg > PAD) deg = PAD;                      // matches dropped writes

    // one coalesced uint per lane = slots {2l, 2l+1}
    unsigned slot = ((const unsigned*)(esrc16 + ((size_t)v << 7)))[lane];
    int s0 = (int)(slot & 0xFFFFu), s1 = (int)(slot >> 16);
    if (2 * lane < deg)     { esw[2 * lane] = s0;     eww[2 * lane] = e[s0]; }
    if (2 * lane + 1 < deg) { esw[2 * lane + 1] = s1; eww[2 * lane + 1] = e[s1]; }

    // pass 1: wave max
    float lm = -3.4e38f;
    for (int i = lane; i < deg; i += 64) lm = fmaxf(lm, eww[i]);
    #pragma unroll
    for (int o = 32; o > 0; o >>= 1) lm = fmaxf(lm, __shfl_xor(lm, o, 64));

    // pass 2: exp weights + wave sum
    float ls = 0.f;
    for (int i = lane; i < deg; i += 64) {
        float p = __expf(eww[i] - lm);
        eww[i] = p; ls += p;
    }
    #pragma unroll
    for (int o = 32; o > 0; o >>= 1) ls += __shfl_xor(ls, o, 64);
    const float inv = (ls > 0.f) ? (1.f / ls) : 0.f;

    // pass 3: weighted bf16 row gather, two 32-lane halves over even/odd edges
    const uint2* zb2 = (const uint2*)zb32;         // row stride 32 uint2
    const int half = lane >> 5, hl = lane & 31;
    float a0 = 0.f, a1 = 0.f, a2 = 0.f, a3 = 0.f;
    int i = half;
    for (; i + 6 < deg; i += 8) {                  // 4 edges per half in flight
        int   t0 = esw[i],  t1 = esw[i + 2],  t2 = esw[i + 4],  t3 = esw[i + 6];
        float w0 = eww[i],  w1 = eww[i + 2],  w2 = eww[i + 4],  w3 = eww[i + 6];
        uint2 u0 = zb2[(size_t)t0 * 32 + hl];
        uint2 u1 = zb2[(size_t)t1 * 32 + hl];
        uint2 u2 = zb2[(size_t)t2 * 32 + hl];
        uint2 u3 = zb2[(size_t)t3 * 32 + hl];
        a0 += w0 * bflo(u0.x); a1 += w0 * bfhi(u0.x);
        a2 += w0 * bflo(u0.y); a3 += w0 * bfhi(u0.y);
        a0 += w1 * bflo(u1.x); a1 += w1 * bfhi(u1.x);
        a2 += w1 * bflo(u1.y); a3 += w1 * bfhi(u1.y);
        a0 += w2 * bflo(u2.x); a1 += w2 * bfhi(u2.x);
        a2 += w2 * bflo(u2.y); a3 += w2 * bfhi(u2.y);
        a0 += w3 * bflo(u3.x); a1 += w3 * bfhi(u3.x);
        a2 += w3 * bflo(u3.y); a3 += w3 * bfhi(u3.y);
    }
    for (; i < deg; i += 2) {
        int s = esw[i]; float p = eww[i];
        uint2 u = zb2[(size_t)s * 32 + hl];
        a0 += p * bflo(u.x); a1 += p * bfhi(u.x);
        a2 += p * bflo(u.y); a3 += p * bfhi(u.y);
    }
    a0 += __shfl_xor(a0, 32, 64);
    a1 += __shfl_xor(a1, 32, 64);
    a2 += __shfl_xor(a2, 32, 64);
    a3 += __shfl_xor(a3, 32, 64);
    if (half == 0) {
        float4 r;
        r.x = a0 * inv; r.y = a1 * inv; r.z = a2 * inv; r.w = a3 * inv;
        *(float4*)&out[(size_t)v * DIM + 4 * hl] = r;
    }
}

// ---------------------------------------------------------------------------
extern "C" void kernel_launch(void* const* d_in, const int* in_sizes, int n_in,
                              void* d_out, int out_size, void* d_ws, size_t ws_size,
                              hipStream_t stream)
{
    const float* h     = (const float*)d_in[0];
    const int*   src   = (const int*)d_in[1];
    const int*   dst   = (const int*)d_in[2];
    const float* Wfc   = (const float*)d_in[3];
    const float* Wattn = (const float*)d_in[4];
    float* out = (float*)d_out;

    // workspace (~10.3 MB), 16B-aligned segments
    unsigned short* zb      = (unsigned short*)d_ws;      // NN*DIM ushort (2.56 MB)
    float*          e       = (float*)(zb + (size_t)NN * DIM);    // 10016 f32
    unsigned char*  bhcnt8  = (unsigned char*)(e + 10016);        // NN*HB uchar (2.56 MB)
    unsigned char*  prefix8 = bhcnt8 + (size_t)NN * HB;           // NN*HB uchar (2.56 MB)
    unsigned char*  deg8    = prefix8 + (size_t)NN * HB;          // NN uchar (+pad)
    unsigned short* esrc16  = (unsigned short*)(deg8 + 10016);    // NN*PAD ushort (2.56 MB)

    histfc_kernel<<<HB + FCB, 512, 0, stream>>>(dst, bhcnt8, h, Wfc, Wattn, zb, e);
    colscan_kernel<<<NN / 4, 256, 0, stream>>>(bhcnt8, prefix8, deg8);
    scatter_kernel<<<HB, 512, 0, stream>>>(src, dst, prefix8, esrc16);
    agg_kernel<<<NN / 4, 256, 0, stream>>>(deg8, esrc16, e, (const unsigned*)zb, out);
}

// Round 18
// 46.112 us; speedup vs baseline: 1.5885x; 1.5885x over previous
//
#include <hip/hip_runtime.h>

#define NN 10000
#define NE 640000
#define DIM 128
#define SB 64                         // scatter blocks; 10000 edges each
#define SEPB (NE / SB)                // 10000
#define FCN 32                        // nodes per fc block
#define FCB ((NN + FCN - 1) / FCN)    // 313 fc blocks
#define DCAP 128                      // max degree (Poisson(64), max ~100)

static __device__ __forceinline__ unsigned short f2bf(float f) {
    unsigned u = __float_as_uint(f);
    unsigned r = (u + 0x7FFFu + ((u >> 16) & 1u)) >> 16;   // RNE
    return (unsigned short)r;
}
static __device__ __forceinline__ float bfhi(unsigned u) { return __uint_as_float(u & 0xFFFF0000u); }
static __device__ __forceinline__ float bflo(unsigned u) { return __uint_as_float(u << 16); }

// ---------------------------------------------------------------------------
// K1: blocks 0..63 = per-block local CSR build (hist -> in-block scan ->
//     compact scatter into private 20KB region). blocks 64..376 = fc.
// ---------------------------------------------------------------------------
__global__ __launch_bounds__(512, 2) void scatfc_kernel(
    const int* __restrict__ src, const int* __restrict__ dst,
    unsigned short* __restrict__ blkoffs,   // [SB][NN+1]
    unsigned short* __restrict__ esrc16,    // [SB][SEPB] compact
    const float* __restrict__ h, const float* __restrict__ W,
    const float* __restrict__ Wa, unsigned short* __restrict__ zb,
    float* __restrict__ e)
{
    __shared__ int smem[10256];                    // 40.1 KB, aliased per role
    const int bid = blockIdx.x, t = threadIdx.x;

    if (bid < SB) {
        int* cnt = smem;                           // [NN]
        int* wsum = smem + 10240;                  // [8]
        int4* c4 = (int4*)cnt;
        for (int i = t; i < NN / 4; i += 512) c4[i] = make_int4(0, 0, 0, 0);
        __syncthreads();

        // pass 1: histogram of this block's 10000 dst
        const int4* d4 = (const int4*)(dst + bid * SEPB);
        const int4* s4 = (const int4*)(src + bid * SEPB);
        for (int i = t; i < SEPB / 4; i += 512) {
            int4 d = d4[i];
            atomicAdd(&cnt[d.x], 1); atomicAdd(&cnt[d.y], 1);
            atomicAdd(&cnt[d.z], 1); atomicAdd(&cnt[d.w], 1);
        }
        __syncthreads();

        // pass 2: exclusive block scan of cnt[10000], in place
        constexpr int C = 20;                      // 512*20 = 10240 >= NN
        const int lane = t & 63, wid = t >> 6;
        int loc[C];
        int base = t * C, s = 0;
        #pragma unroll
        for (int j = 0; j < C; ++j) {
            int idx = base + j;
            int v = (idx < NN) ? cnt[idx] : 0;
            loc[j] = s; s += v;
        }
        int x = s;
        #pragma unroll
        for (int o = 1; o <= 32; o <<= 1) {
            int y = __shfl_up(x, o, 64);
            if (lane >= o) x += y;
        }
        if (lane == 63) wsum[wid] = x;
        __syncthreads();
        if (t == 0) {
            int run = 0;
            #pragma unroll
            for (int i2 = 0; i2 < 8; ++i2) { int tmp = wsum[i2]; wsum[i2] = run; run += tmp; }
        }
        __syncthreads();
        const int texcl = wsum[wid] + (x - s);
        #pragma unroll
        for (int j = 0; j < C; ++j) {
            int idx = base + j;
            if (idx < NN) cnt[idx] = texcl + loc[j];
        }
        __syncthreads();

        // save per-block offsets (coalesced ushort; sentinel = 10000)
        unsigned short* bo = blkoffs + (size_t)bid * (NN + 1);
        for (int v = t; v < NN; v += 512) bo[v] = (unsigned short)cnt[v];
        if (t == 0) bo[NN] = (unsigned short)SEPB;
        __syncthreads();                           // bo saved before cursors destroyed

        // pass 3: scatter, cnt[] as cursor; private compact 20KB region
        unsigned short* eo = esrc16 + (size_t)bid * SEPB;
        for (int i = t; i < SEPB / 4; i += 512) {
            int4 d = d4[i]; int4 sv = s4[i];
            int r;
            r = atomicAdd(&cnt[d.x], 1); eo[r] = (unsigned short)sv.x;
            r = atomicAdd(&cnt[d.y], 1); eo[r] = (unsigned short)sv.y;
            r = atomicAdd(&cnt[d.z], 1); eo[r] = (unsigned short)sv.z;
            r = atomicAdd(&cnt[d.w], 1); eo[r] = (unsigned short)sv.w;
        }
    } else {
        // ---- fc: z(bf16) = h @ W^T via LDS-transposed W tiles (R13-proven) ----
        float* hs = (float*)smem;                  // [32][128] = 16 KB
        float* wt = hs + FCN * DIM;                // [32][132] = 16.5 KB
        const int jl = t & 31, jq = jl * 4;
        const int ng = t >> 5;                     // 0..15, 2 nodes each
        const int i0 = (bid - SB) * FCN;

        const float4* h4 = (const float4*)h;
        float4* hs4 = (float4*)hs;
        #pragma unroll
        for (int p = 0; p < 2; ++p) {              // 32 nodes x 32 float4
            int u = t + p * 512;
            int gi = i0 + (u >> 5);
            hs4[u] = (gi < NN) ? h4[(size_t)gi * 32 + (u & 31)]
                               : make_float4(0.f, 0.f, 0.f, 0.f);
        }

        const float4* W4 = (const float4*)W;
        float acc[2][4] = {};
        for (int kt = 0; kt < 4; ++kt) {           // 4 k-tiles of 32
            __syncthreads();                       // hs ready / wt reuse guard
            #pragma unroll
            for (int p = 0; p < 2; ++p) {          // 128 rows x 8 float4
                int idx = t + p * 512;
                int row = idx >> 3, q4 = idx & 7;
                float4 wv = W4[(size_t)row * 32 + kt * 8 + q4];   // coalesced
                wt[(q4 * 4 + 0) * 132 + row] = wv.x;
                wt[(q4 * 4 + 1) * 132 + row] = wv.y;
                wt[(q4 * 4 + 2) * 132 + row] = wv.z;
                wt[(q4 * 4 + 3) * 132 + row] = wv.w;
            }
            __syncthreads();
            #pragma unroll
            for (int kk4 = 0; kk4 < 8; ++kk4) {
                float4 wj0 = *(const float4*)&wt[(kk4 * 4 + 0) * 132 + jq];
                float4 wj1 = *(const float4*)&wt[(kk4 * 4 + 1) * 132 + jq];
                float4 wj2 = *(const float4*)&wt[(kk4 * 4 + 2) * 132 + jq];
                float4 wj3 = *(const float4*)&wt[(kk4 * 4 + 3) * 132 + jq];
                #pragma unroll
                for (int m = 0; m < 2; ++m) {
                    float4 hv = *(const float4*)&hs[(2 * ng + m) * DIM + kt * 32 + kk4 * 4];
                    acc[m][0] += hv.x * wj0.x + hv.y * wj1.x + hv.z * wj2.x + hv.w * wj3.x;
                    acc[m][1] += hv.x * wj0.y + hv.y * wj1.y + hv.z * wj2.y + hv.w * wj3.y;
                    acc[m][2] += hv.x * wj0.z + hv.y * wj1.z + hv.z * wj2.z + hv.w * wj3.z;
                    acc[m][3] += hv.x * wj0.w + hv.y * wj1.w + hv.z * wj2.w + hv.w * wj3.w;
                }
            }
        }

        const float a0 = Wa[jq], a1 = Wa[jq + 1], a2 = Wa[jq + 2], a3 = Wa[jq + 3];
        #pragma unroll
        for (int m = 0; m < 2; ++m) {
            int gi = i0 + 2 * ng + m;
            float ep = acc[m][0] * a0 + acc[m][1] * a1 + acc[m][2] * a2 + acc[m][3] * a3;
            #pragma unroll
            for (int o = 16; o > 0; o >>= 1) ep += __shfl_xor(ep, o, 64);
            if (gi < NN) {
                ushort4 zo;
                zo.x = f2bf(acc[m][0]); zo.y = f2bf(acc[m][1]);
                zo.z = f2bf(acc[m][2]); zo.w = f2bf(acc[m][3]);
                *(ushort4*)&zb[(size_t)gi * DIM + jq] = zo;
                if (jl == 0) e[gi] = ep;
            }
        }
    }
}

// ---------------------------------------------------------------------------
// K2: agg. 4 waves/block, one node per wave, no barriers. Lane l owns block
// l's cell for node v: [start,end) from blkoffs -> wave prefix -> dense LDS
// compaction -> softmax -> weighted bf16 gather (proven R10+).
// ---------------------------------------------------------------------------
__global__ __launch_bounds__(256) void agg_kernel(
    const unsigned short* __restrict__ blkoffs, const unsigned short* __restrict__ esrc16,
    const float* __restrict__ e, const unsigned* __restrict__ zb32,
    float* __restrict__ out)
{
    __shared__ int   es[4][DCAP];
    __shared__ float ew[4][DCAP];
    const int w = threadIdx.x >> 6, lane = threadIdx.x & 63;
    const int v = blockIdx.x * 4 + w;              // 2500*4 = 10000 exact
    int* esw = es[w];
    float* eww = ew[w];

    // own cell bounds (two ushort loads, L2-hot 1.28 MB array)
    const unsigned short* bo = blkoffs + (size_t)lane * (NN + 1) + v;
    const int start = bo[0];
    const int cell  = bo[1] - start;

    // wave prefix over cell counts
    int x = cell;
    #pragma unroll
    for (int o = 1; o <= 32; o <<= 1) {
        int y = __shfl_up(x, o, 64);
        if (lane >= o) x += y;
    }
    int deg = __shfl(x, 63, 64);
    if (deg > DCAP) deg = DCAP;
    int base = x - cell;

    // compact own entries into dense LDS (cell avg 1, max ~9)
    const unsigned short* ep = esrc16 + (size_t)lane * SEPB + start;
    for (int j = 0; j < cell; ++j) {
        int tgt = base + j;
        if (tgt < DCAP) {
            int s = ep[j];
            esw[tgt] = s;
            eww[tgt] = e[s];                       // random e gather (L2-hot 40KB)
        }
    }

    // pass 1: wave max
    float lm = -3.4e38f;
    for (int i = lane; i < deg; i += 64) lm = fmaxf(lm, eww[i]);
    #pragma unroll
    for (int o = 32; o > 0; o >>= 1) lm = fmaxf(lm, __shfl_xor(lm, o, 64));

    // pass 2: exp weights + wave sum
    float ls = 0.f;
    for (int i = lane; i < deg; i += 64) {
        float p = __expf(eww[i] - lm);             // same-lane LDS RAW
        eww[i] = p; ls += p;
    }
    #pragma unroll
    for (int o = 32; o > 0; o >>= 1) ls += __shfl_xor(ls, o, 64);
    const float inv = (ls > 0.f) ? (1.f / ls) : 0.f;

    // pass 3: weighted bf16 row gather, two 32-lane halves over even/odd edges
    const uint2* zb2 = (const uint2*)zb32;         // row stride 32 uint2
    const int half = lane >> 5, hl = lane & 31;
    float a0 = 0.f, a1 = 0.f, a2 = 0.f, a3 = 0.f;
    int i = half;
    for (; i + 6 < deg; i += 8) {                  // 4 edges per half in flight
        int   t0 = esw[i],  t1 = esw[i + 2],  t2 = esw[i + 4],  t3 = esw[i + 6];
        float w0 = eww[i],  w1 = eww[i + 2],  w2 = eww[i + 4],  w3 = eww[i + 6];
        uint2 u0 = zb2[(size_t)t0 * 32 + hl];
        uint2 u1 = zb2[(size_t)t1 * 32 + hl];
        uint2 u2 = zb2[(size_t)t2 * 32 + hl];
        uint2 u3 = zb2[(size_t)t3 * 32 + hl];
        a0 += w0 * bflo(u0.x); a1 += w0 * bfhi(u0.x);
        a2 += w0 * bflo(u0.y); a3 += w0 * bfhi(u0.y);
        a0 += w1 * bflo(u1.x); a1 += w1 * bfhi(u1.x);
        a2 += w1 * bflo(u1.y); a3 += w1 * bfhi(u1.y);
        a0 += w2 * bflo(u2.x); a1 += w2 * bfhi(u2.x);
        a2 += w2 * bflo(u2.y); a3 += w2 * bfhi(u2.y);
        a0 += w3 * bflo(u3.x); a1 += w3 * bfhi(u3.x);
        a2 += w3 * bflo(u3.y); a3 += w3 * bfhi(u3.y);
    }
    for (; i < deg; i += 2) {
        int s = esw[i]; float p = eww[i];
        uint2 u = zb2[(size_t)s * 32 + hl];
        a0 += p * bflo(u.x); a1 += p * bfhi(u.x);
        a2 += p * bflo(u.y); a3 += p * bfhi(u.y);
    }
    a0 += __shfl_xor(a0, 32, 64);
    a1 += __shfl_xor(a1, 32, 64);
    a2 += __shfl_xor(a2, 32, 64);
    a3 += __shfl_xor(a3, 32, 64);
    if (half == 0) {
        float4 r;
        r.x = a0 * inv; r.y = a1 * inv; r.z = a2 * inv; r.w = a3 * inv;
        *(float4*)&out[(size_t)v * DIM + 4 * hl] = r;
    }
}

// ---------------------------------------------------------------------------
extern "C" void kernel_launch(void* const* d_in, const int* in_sizes, int n_in,
                              void* d_out, int out_size, void* d_ws, size_t ws_size,
                              hipStream_t stream)
{
    const float* h     = (const float*)d_in[0];
    const int*   src   = (const int*)d_in[1];
    const int*   dst   = (const int*)d_in[2];
    const float* Wfc   = (const float*)d_in[3];
    const float* Wattn = (const float*)d_in[4];
    float* out = (float*)d_out;

    // workspace (~5.2 MB), 16B-aligned segments
    unsigned short* zb      = (unsigned short*)d_ws;              // NN*DIM ushort (2.56 MB)
    float*          e       = (float*)(zb + (size_t)NN * DIM);    // 10016 f32
    unsigned short* blkoffs = (unsigned short*)(e + 10016);       // SB*(NN+1) ushort (1.28 MB)
    unsigned short* esrc16  = blkoffs + (size_t)SB * (NN + 1) + 16; // SB*SEPB ushort (1.28 MB)

    scatfc_kernel<<<SB + FCB, 512, 0, stream>>>(src, dst, blkoffs, esrc16,
                                                h, Wfc, Wattn, zb, e);
    agg_kernel<<<NN / 4, 256, 0, stream>>>(blkoffs, esrc16, e, (const unsigned*)zb, out);
}